// Round 4
// baseline (1146.123 us; speedup 1.0000x reference)
//
#include <hip/hip_runtime.h>

// VSGNet fused pipeline — fp32 in/out (per reference dtypes), bf16 MFMA compute.
// B=64 P=16 L=16 D=1024 SP=32 PROJ=512 ACT=29, C=16384.
// Factorizations: pairs@Wvis = Pp[b*16+p]+Po[b*16+l]+Pc[b];
// p_graph = people@Wg_p + adj@(oh@Wg_p) + objects@Wg_o [+ adjT@(ho@Wg_o), l>=1] + bg.
// Rounds 1-3 NaN root cause: inputs are FP32 (reference setup_inputs is jnp.float32);
// reading them as bf16 makes fp32 mantissa low-halves decode to Inf/NaN (~1/256 per
// element). All input loads now fp32 with on-the-fly RNE bf16 conversion for MFMA.

typedef unsigned short u16;   // bf16 bits
typedef short s16x8 __attribute__((ext_vector_type(8)));
typedef float f32x4 __attribute__((ext_vector_type(4)));

__device__ __forceinline__ u16 f2b(float f) {
    union { float f; unsigned int i; } v; v.f = f;
    unsigned int r = (v.i + 0x7fffu + ((v.i >> 16) & 1u)) >> 16;  // RNE
    return (u16)r;
}
__device__ __forceinline__ float b2f(u16 u) {
    union { float f; unsigned int i; } v; v.i = ((unsigned int)u) << 16; return v.f;
}
// load 8 consecutive fp32, convert to bf16 MFMA fragment
__device__ __forceinline__ s16x8 ld8(const float* p) {
    float4 a = *(const float4*)p;
    float4 b = *(const float4*)(p + 4);
    s16x8 r;
    r[0] = (short)f2b(a.x); r[1] = (short)f2b(a.y);
    r[2] = (short)f2b(a.z); r[3] = (short)f2b(a.w);
    r[4] = (short)f2b(b.x); r[5] = (short)f2b(b.y);
    r[6] = (short)f2b(b.z); r[7] = (short)f2b(b.w);
    return r;
}

// ---------------- workspace layout (bytes), total 2,973,696 ----------------
#define OFF_WSPATT 0u         // [512][32]  bf16
#define OFF_WREFT  32768u     // [32][512]  bf16 (rows 29..31 zero)
#define OFF_WATTT  65536u     // [32][512]  bf16
#define OFF_WGT    98304u     // [32][2048] bf16
#define OFF_PP     229376u    // [1024][512] bf16
#define OFF_PO     1277952u   // [1024][512] bf16
#define OFF_PC     2326528u   // [64][512]  bf16
#define OFF_ADJ    2392064u   // [16384] f32
#define OFF_HP     2457600u   // [1024][32] f32  people@Wg_p
#define OFF_HOF    2588672u   // [1024][32] f32  objects@Wg_o
#define OFF_YH     2719744u   // [1024][32] f32  relu(people@Who+b)@Wg_o
#define OFF_ZO     2850816u   // [960][32]  f32  relu(obj[:,1:]@Woh+b)@Wg_p

// ---------------- small-weight transposes (fp32 src -> bf16 ws) -------------
__global__ __launch_bounds__(256) void transpose_small(
    const float* __restrict__ Wspat, const float* __restrict__ Wref,
    const float* __restrict__ Watt, const float* __restrict__ Wg,
    u16* __restrict__ WspatT, u16* __restrict__ WrefT,
    u16* __restrict__ WattT, u16* __restrict__ WgT)
{
    int g = blockIdx.x * 256 + threadIdx.x;
    int gsz = gridDim.x * 256;
    for (int i = g; i < 512 * 32; i += gsz) {          // WspatT[n][k] <- Wspat[k][n]
        int n = i >> 5, k = i & 31;
        WspatT[i] = f2b(Wspat[k * 512 + n]);
    }
    for (int i = g; i < 32 * 512; i += gsz) {          // WrefT[n][k] <- Wref[k][n<29]
        int n = i >> 9, k = i & 511;
        WrefT[i] = (n < 29) ? f2b(Wref[k * 29 + n]) : (u16)0;
    }
    for (int i = g; i < 32 * 512; i += gsz) {
        int n = i >> 9, k = i & 511;
        WattT[i] = (n < 29) ? f2b(Watt[k * 29 + n]) : (u16)0;
    }
    for (int i = g; i < 32 * 2048; i += gsz) {         // WgT[n][k] <- Wg[k][n<29]
        int n = i >> 11, k = i & 2047;
        WgT[i] = (n < 29) ? f2b(Wg[k * 29 + n]) : (u16)0;
    }
}

// ---- C[M,N] = A[M,K] @ W[K,N]. A,W fp32 (row-major); W LDS-transposed to bf16.
// Block tile 64x64, 4 waves 2x2 (each 32x32). Grid (N/64, M/64). K%32==0.
// Output bf16 (workspace operand for later fusion).
__global__ __launch_bounds__(256) void gemm_nt(
    const float* __restrict__ A, int lda,
    const float* __restrict__ W, int ldw,
    u16* __restrict__ outB, int ldo, int K)
{
    __shared__ u16 WT[64][40];   // [n_loc][k_loc], +8 pad
    int t = threadIdx.x;
    int lane = t & 63, w = t >> 6;
    int l16 = lane & 15, q = lane >> 4;
    int wy = w >> 1, wx = w & 1;
    int bm = blockIdx.y * 64 + wy * 32;
    int bn = blockIdx.x * 64;

    const float* ap0 = A + (size_t)(bm + l16) * lda + q * 8;
    const float* ap1 = A + (size_t)(bm + 16 + l16) * lda + q * 8;
    int kst = t >> 3;            // 0..31
    int nst = (t & 7) * 8;       // 0..56
    const float* wp = W + (size_t)kst * ldw + bn + nst;

    f32x4 acc00 = {0,0,0,0}, acc01 = {0,0,0,0}, acc10 = {0,0,0,0}, acc11 = {0,0,0,0};
    for (int k0 = 0; k0 < K; k0 += 32) {
        float4 w0 = *(const float4*)wp;
        float4 w1 = *(const float4*)(wp + 4);
        wp += (size_t)32 * ldw;
        __syncthreads();
        WT[nst + 0][kst] = f2b(w0.x); WT[nst + 1][kst] = f2b(w0.y);
        WT[nst + 2][kst] = f2b(w0.z); WT[nst + 3][kst] = f2b(w0.w);
        WT[nst + 4][kst] = f2b(w1.x); WT[nst + 5][kst] = f2b(w1.y);
        WT[nst + 6][kst] = f2b(w1.z); WT[nst + 7][kst] = f2b(w1.w);
        __syncthreads();
        s16x8 a0 = ld8(ap0); ap0 += 32;
        s16x8 a1 = ld8(ap1); ap1 += 32;
        s16x8 b0 = *(const s16x8*)(&WT[wx * 32 + l16][q * 8]);
        s16x8 b1 = *(const s16x8*)(&WT[wx * 32 + 16 + l16][q * 8]);
        acc00 = __builtin_amdgcn_mfma_f32_16x16x32_bf16(a0, b0, acc00, 0, 0, 0);
        acc01 = __builtin_amdgcn_mfma_f32_16x16x32_bf16(a0, b1, acc01, 0, 0, 0);
        acc10 = __builtin_amdgcn_mfma_f32_16x16x32_bf16(a1, b0, acc10, 0, 0, 0);
        acc11 = __builtin_amdgcn_mfma_f32_16x16x32_bf16(a1, b1, acc11, 0, 0, 0);
    }
    f32x4 accs[2][2] = {{acc00, acc01}, {acc10, acc11}};
#pragma unroll
    for (int ii = 0; ii < 2; ii++)
#pragma unroll
        for (int jj = 0; jj < 2; jj++) {
            int col = bn + wx * 32 + jj * 16 + l16;
#pragma unroll
            for (int r = 0; r < 4; r++) {
                int row = bm + ii * 16 + q * 4 + r;
                outB[(size_t)row * ldo + col] = f2b(accs[ii][jj][r]);
            }
        }
}

// ---- U[32rows][32] f32 = relu(A32 @ W1[1024][1024] + b1) @ WgT2^T -----------
// A,W1,b1 fp32; WgT2 bf16 [32 n][2048 k] (pre-offset). rowmap 1=skip-slot0.
__global__ __launch_bounds__(256) void relu_proj(
    const float* __restrict__ A, int rowmap,
    const float* __restrict__ W1, const float* __restrict__ b1,
    const u16* __restrict__ WgT2, float* __restrict__ U)
{
    __shared__ u16 T[32][1032];   // relu intermediate (bf16), +8 pad
    __shared__ u16 WT[64][40];
    int t = threadIdx.x;
    int lane = t & 63, w = t >> 6;
    int l16 = lane & 15, q = lane >> 4;
    int wy = w >> 1, wx = w & 1;
    int m0 = blockIdx.x * 32;

    int r = m0 + wy * 16 + l16;
    if (rowmap == 1) r = (r / 15) * 16 + (r % 15) + 1;
    const float* arow = A + (size_t)r * 1024;

    int kst = t >> 3, nst = (t & 7) * 8;

    for (int nt = 0; nt < 16; nt++) {
        int nb = nt * 64;
        f32x4 acc0 = {0,0,0,0}, acc1 = {0,0,0,0};
        const float* wp = W1 + (size_t)kst * 1024 + nb + nst;
        for (int k0 = 0; k0 < 1024; k0 += 32) {
            float4 w0 = *(const float4*)wp;
            float4 w1 = *(const float4*)(wp + 4);
            wp += 32 * 1024;
            __syncthreads();
            WT[nst + 0][kst] = f2b(w0.x); WT[nst + 1][kst] = f2b(w0.y);
            WT[nst + 2][kst] = f2b(w0.z); WT[nst + 3][kst] = f2b(w0.w);
            WT[nst + 4][kst] = f2b(w1.x); WT[nst + 5][kst] = f2b(w1.y);
            WT[nst + 6][kst] = f2b(w1.z); WT[nst + 7][kst] = f2b(w1.w);
            __syncthreads();
            s16x8 a = ld8(arow + k0 + q * 8);
            s16x8 b0 = *(const s16x8*)(&WT[wx * 32 + l16][q * 8]);
            s16x8 b1 = *(const s16x8*)(&WT[wx * 32 + 16 + l16][q * 8]);
            acc0 = __builtin_amdgcn_mfma_f32_16x16x32_bf16(a, b0, acc0, 0, 0, 0);
            acc1 = __builtin_amdgcn_mfma_f32_16x16x32_bf16(a, b1, acc1, 0, 0, 0);
        }
#pragma unroll
        for (int jj = 0; jj < 2; jj++) {
            int col = nb + wx * 32 + jj * 16 + l16;
            float bv = b1[col];
#pragma unroll
            for (int rr = 0; rr < 4; rr++) {
                float v = (jj ? acc1[rr] : acc0[rr]) + bv;
                T[wy * 16 + q * 4 + rr][col] = f2b(fmaxf(v, 0.f));
            }
        }
    }
    __syncthreads();

    // stage 2: U = T @ WgT2^T (32x32, K=1024); 4 waves 2x2
    int rt = w >> 1, ct = w & 1;
    f32x4 acc = {0,0,0,0};
    for (int k0 = 0; k0 < 1024; k0 += 32) {
        s16x8 a = *(const s16x8*)(&T[rt * 16 + l16][k0 + q * 8]);
        s16x8 b = *(const s16x8*)(WgT2 + (size_t)(ct * 16 + l16) * 2048 + k0 + q * 8);
        acc = __builtin_amdgcn_mfma_f32_16x16x32_bf16(a, b, acc, 0, 0, 0);
    }
    int col = ct * 16 + l16;
#pragma unroll
    for (int rr = 0; rr < 4; rr++)
        U[(size_t)(m0 + rt * 16 + q * 4 + rr) * 32 + col] = acc[rr];
}

// ---- out[1024][32] f32 = A[1024][1024] fp32 @ BT^T (BT [32][2048] bf16) -----
__global__ __launch_bounds__(256) void gemm_bt32(
    const float* __restrict__ A, const u16* __restrict__ BT,
    float* __restrict__ outF)
{
    int t = threadIdx.x, lane = t & 63, w = t >> 6;
    int l16 = lane & 15, q = lane >> 4;
    int bm = blockIdx.x * 128 + w * 32;
    const float* ap0 = A + (size_t)(bm + l16) * 1024 + q * 8;
    const float* ap1 = A + (size_t)(bm + 16 + l16) * 1024 + q * 8;
    const u16* bp0 = BT + (size_t)l16 * 2048 + q * 8;
    const u16* bp1 = BT + (size_t)(16 + l16) * 2048 + q * 8;
    f32x4 acc00 = {0,0,0,0}, acc01 = {0,0,0,0}, acc10 = {0,0,0,0}, acc11 = {0,0,0,0};
    for (int k = 0; k < 1024; k += 32) {
        s16x8 a0 = ld8(ap0); ap0 += 32;
        s16x8 a1 = ld8(ap1); ap1 += 32;
        s16x8 b0 = *(const s16x8*)bp0; bp0 += 32;
        s16x8 b1 = *(const s16x8*)bp1; bp1 += 32;
        acc00 = __builtin_amdgcn_mfma_f32_16x16x32_bf16(a0, b0, acc00, 0, 0, 0);
        acc01 = __builtin_amdgcn_mfma_f32_16x16x32_bf16(a0, b1, acc01, 0, 0, 0);
        acc10 = __builtin_amdgcn_mfma_f32_16x16x32_bf16(a1, b0, acc10, 0, 0, 0);
        acc11 = __builtin_amdgcn_mfma_f32_16x16x32_bf16(a1, b1, acc11, 0, 0, 0);
    }
    f32x4 accs[2][2] = {{acc00, acc01}, {acc10, acc11}};
#pragma unroll
    for (int ii = 0; ii < 2; ii++)
#pragma unroll
        for (int jj = 0; jj < 2; jj++)
#pragma unroll
            for (int r = 0; r < 4; r++)
                outF[(size_t)(bm + ii * 16 + q * 4 + r) * 32 + jj * 16 + l16] =
                    accs[ii][jj][r];
}

// ---- mega: per 32-row tile: aho(MFMA) -> p_att -> fref(in-place LDS)+i_ho -> p_ref
__global__ __launch_bounds__(256) void mega(
    const float* __restrict__ spatial, const u16* __restrict__ WspatT,
    const float* __restrict__ bspat,
    const u16* __restrict__ Pp, const u16* __restrict__ Po,
    const u16* __restrict__ Pc, const float* __restrict__ bvis,
    const u16* __restrict__ WrefT, const float* __restrict__ bref,
    const u16* __restrict__ WattT, const float* __restrict__ batt,
    const float* __restrict__ wip, const float* __restrict__ bip,
    float* __restrict__ outI, float* __restrict__ outRef,
    float* __restrict__ outAtt, float* __restrict__ adjw)
{
    __shared__ u16 tile[32][512];
    __shared__ float part[32][8];
    __shared__ float wipS[512];
    int t = threadIdx.x;
    int c0 = blockIdx.x * 32;
    int lane = t & 63, w = t >> 6;
    int l16 = lane & 15, q = lane >> 4;

    {
        float2 u = *(const float2*)(wip + t * 2);
        wipS[t * 2]     = u.x;
        wipS[t * 2 + 1] = u.y;
    }

    // step 1: aho rows c0..c0+31; wave w owns cols [w*128, w*128+128)
    {
        s16x8 a0 = ld8(spatial + (size_t)(c0 + l16) * 32 + q * 8);
        s16x8 a1 = ld8(spatial + (size_t)(c0 + 16 + l16) * 32 + q * 8);
#pragma unroll
        for (int nt = 0; nt < 8; nt++) {
            int n = w * 128 + nt * 16;
            s16x8 b = *(const s16x8*)(WspatT + (size_t)(n + l16) * 32 + q * 8);
            f32x4 acc0 = {0,0,0,0}, acc1 = {0,0,0,0};
            acc0 = __builtin_amdgcn_mfma_f32_16x16x32_bf16(a0, b, acc0, 0, 0, 0);
            acc1 = __builtin_amdgcn_mfma_f32_16x16x32_bf16(a1, b, acc1, 0, 0, 0);
            float bias = bspat[n + l16];
#pragma unroll
            for (int r = 0; r < 4; r++) {
                tile[q * 4 + r][n + l16]      = f2b(fmaxf(acc0[r] + bias, 0.f));
                tile[16 + q * 4 + r][n + l16] = f2b(fmaxf(acc1[r] + bias, 0.f));
            }
        }
    }
    __syncthreads();

    // step 2: p_att = aho @ WattT^T + batt
    {
        int rt = w >> 1, ct = w & 1;
        f32x4 acc = {0,0,0,0};
        for (int k = 0; k < 512; k += 32) {
            s16x8 a = *(const s16x8*)(&tile[rt * 16 + l16][k + q * 8]);
            s16x8 b = *(const s16x8*)(WattT + (size_t)(ct * 16 + l16) * 512 + k + q * 8);
            acc = __builtin_amdgcn_mfma_f32_16x16x32_bf16(a, b, acc, 0, 0, 0);
        }
        int col = ct * 16 + l16;
        if (col < 29) {
            float bias = batt[col];
#pragma unroll
            for (int r = 0; r < 4; r++) {
                int row = c0 + rt * 16 + q * 4 + r;
                outAtt[(size_t)row * 29 + col] = acc[r] + bias;
            }
        }
    }
    __syncthreads();   // all reads of aho done before in-place overwrite

    // step 3: fref = relu(Pp+Po+Pc+bvis) * aho (in-place); i_ho partials
    {
        int row = t >> 3, g = t & 7;
        int c = c0 + row;
        int rp = c >> 4, bimg = c >> 8;
        int ro = bimg * 16 + (c & 15);
        const u16* ppr = Pp + (size_t)rp * 512;
        const u16* por = Po + (size_t)ro * 512;
        const u16* pcr = Pc + (size_t)bimg * 512;
        float ps = 0.f;
#pragma unroll 4
        for (int j = 0; j < 64; j += 2) {
            int col = g * 64 + j;
            unsigned int upp = *(const unsigned int*)(ppr + col);
            unsigned int upo = *(const unsigned int*)(por + col);
            unsigned int upc = *(const unsigned int*)(pcr + col);
            float2 bv = *(const float2*)(bvis + col);
            unsigned int uah = *(const unsigned int*)(&tile[row][col]);
            float fv0 = fmaxf(b2f((u16)(upp & 0xffff)) + b2f((u16)(upo & 0xffff))
                            + b2f((u16)(upc & 0xffff)) + bv.x, 0.f);
            float fv1 = fmaxf(b2f((u16)(upp >> 16)) + b2f((u16)(upo >> 16))
                            + b2f((u16)(upc >> 16)) + bv.y, 0.f);
            float fr0 = fv0 * b2f((u16)(uah & 0xffff));
            float fr1 = fv1 * b2f((u16)(uah >> 16));
            *(unsigned int*)(&tile[row][col]) =
                (unsigned int)f2b(fr0) | ((unsigned int)f2b(fr1) << 16);
            ps += fr0 * wipS[col] + fr1 * wipS[col + 1];
        }
        part[row][g] = ps;
    }
    __syncthreads();

    if (t < 32) {
        float s = part[t][0] + part[t][1] + part[t][2] + part[t][3]
                + part[t][4] + part[t][5] + part[t][6] + part[t][7] + bip[0];
        outI[c0 + t] = s;
        adjw[c0 + t] = 1.f / (1.f + expf(-s));
    }

    // step 4: p_ref = fref @ WrefT^T + bref
    {
        int rt = w >> 1, ct = w & 1;
        f32x4 acc = {0,0,0,0};
        for (int k = 0; k < 512; k += 32) {
            s16x8 a = *(const s16x8*)(&tile[rt * 16 + l16][k + q * 8]);
            s16x8 b = *(const s16x8*)(WrefT + (size_t)(ct * 16 + l16) * 512 + k + q * 8);
            acc = __builtin_amdgcn_mfma_f32_16x16x32_bf16(a, b, acc, 0, 0, 0);
        }
        int col = ct * 16 + l16;
        if (col < 29) {
            float bias = bref[col];
#pragma unroll
            for (int r = 0; r < 4; r++) {
                int row = c0 + rt * 16 + q * 4 + r;
                outRef[(size_t)row * 29 + col] = acc[r] + bias;
            }
        }
    }
}

// ---- p_graph: per image, tiny adj contractions + broadcast sum -------------
__global__ __launch_bounds__(256) void pgraph2(
    const float* __restrict__ adjw, const float* __restrict__ Hp,
    const float* __restrict__ HoF, const float* __restrict__ Yh,
    const float* __restrict__ Zo, const float* __restrict__ bg,
    float* __restrict__ outG)
{
    int b = blockIdx.x, t = threadIdx.x;
    __shared__ float adjS[16][16];
    __shared__ float YhS[16][32];
    __shared__ float ZoS[15][32];
    __shared__ float PA[16][32];
    __shared__ float OA[16][32];
    adjS[t >> 4][t & 15] = adjw[b * 256 + t];
    for (int i = t; i < 512; i += 256)
        YhS[i >> 5][i & 31] = Yh[(size_t)(b * 16 + (i >> 5)) * 32 + (i & 31)];
    for (int i = t; i < 480; i += 256)
        ZoS[i >> 5][i & 31] = Zo[(size_t)(b * 15 + (i >> 5)) * 32 + (i & 31)];
    __syncthreads();
    for (int i = t; i < 512; i += 256) {
        int p = i >> 5, j = i & 31;
        float s = 0.f;
#pragma unroll
        for (int o = 0; o < 15; o++) s += adjS[p][o + 1] * ZoS[o][j];
        PA[p][j] = s;
        float s2 = 0.f;
#pragma unroll
        for (int pp = 0; pp < 16; pp++) s2 += adjS[pp][p] * YhS[pp][j];
        OA[p][j] = s2;          // valid for slot index >=1; [0] unused
    }
    __syncthreads();
    int p = t >> 4, l = t & 15;
    const float* hp = Hp + (size_t)(b * 16 + p) * 32;
    const float* ho = HoF + (size_t)(b * 16 + l) * 32;
    size_t c = (size_t)b * 256 + t;
    for (int j = 0; j < 29; j++) {
        float v = hp[j] + ho[j] + bg[j] + PA[p][j];
        if (l >= 1) v += OA[l][j];
        outG[c * 29 + j] = v;
    }
}

extern "C" void kernel_launch(void* const* d_in, const int* in_sizes, int n_in,
                              void* d_out, int out_size, void* d_ws, size_t ws_size,
                              hipStream_t stream)
{
    const float* people  = (const float*)d_in[0];
    const float* objects = (const float*)d_in[1];
    const float* context = (const float*)d_in[2];
    const float* spatial = (const float*)d_in[3];
    const float* Wvis_w  = (const float*)d_in[4];
    const float* Wvis_b  = (const float*)d_in[5];
    const float* Wspat_w = (const float*)d_in[6];
    const float* Wspat_b = (const float*)d_in[7];
    const float* Wip_w   = (const float*)d_in[8];
    const float* Wip_b   = (const float*)d_in[9];
    const float* Wref_w  = (const float*)d_in[10];
    const float* Wref_b  = (const float*)d_in[11];
    const float* Watt_w  = (const float*)d_in[12];
    const float* Watt_b  = (const float*)d_in[13];
    const float* Woh_w   = (const float*)d_in[14];
    const float* Woh_b   = (const float*)d_in[15];
    const float* Who_w   = (const float*)d_in[16];
    const float* Who_b   = (const float*)d_in[17];
    const float* Wg_w    = (const float*)d_in[18];
    const float* Wg_b    = (const float*)d_in[19];

    char* ws = (char*)d_ws;
    u16* WspatT = (u16*)(ws + OFF_WSPATT);
    u16* WrefT  = (u16*)(ws + OFF_WREFT);
    u16* WattT  = (u16*)(ws + OFF_WATTT);
    u16* WgT    = (u16*)(ws + OFF_WGT);
    u16* Ppb    = (u16*)(ws + OFF_PP);
    u16* Pob    = (u16*)(ws + OFF_PO);
    u16* Pcb    = (u16*)(ws + OFF_PC);
    float* adjw = (float*)(ws + OFF_ADJ);
    float* Hp   = (float*)(ws + OFF_HP);
    float* HoF  = (float*)(ws + OFF_HOF);
    float* Yh   = (float*)(ws + OFF_YH);
    float* Zo   = (float*)(ws + OFF_ZO);

    float* outI   = (float*)d_out;        // i_ho   [16384]
    float* outRef = outI + 16384;         // p_ref  [16384,29]
    float* outAtt = outI + 491520;        // p_att  [16384,29]
    float* outG   = outI + 966656;        // p_graph[16384,29]

    // 1) small-weight transposes (224 KB bf16)
    transpose_small<<<256, 256, 0, stream>>>(Wspat_w, Wref_w, Watt_w, Wg_w,
                                             WspatT, WrefT, WattT, WgT);

    // 2) Pp/Po/Pc = {people,objects,context} @ Wvis slices (LDS-transposed W)
    gemm_nt<<<dim3(8, 16), 256, 0, stream>>>(people, 1024,
        Wvis_w, 512, Ppb, 512, 1024);
    gemm_nt<<<dim3(8, 16), 256, 0, stream>>>(objects, 1024,
        Wvis_w + (size_t)1024 * 512, 512, Pob, 512, 1024);
    gemm_nt<<<dim3(8, 1), 256, 0, stream>>>(context, 1024,
        Wvis_w + (size_t)2048 * 512, 512, Pcb, 512, 1024);

    // 3) fused aho / p_att / fref / i_ho / p_ref
    mega<<<512, 256, 0, stream>>>(spatial, WspatT, Wspat_b,
                                  Ppb, Pob, Pcb, Wvis_b,
                                  WrefT, Wref_b, WattT, Watt_b,
                                  Wip_w, Wip_b,
                                  outI, outRef, outAtt, adjw);

    // 4) graph-head projections (message passing pushed through Wg)
    relu_proj<<<32, 256, 0, stream>>>(people, 0, Who_w, Who_b, WgT + 1024, Yh);
    relu_proj<<<30, 256, 0, stream>>>(objects, 1, Woh_w, Woh_b, WgT, Zo);
    gemm_bt32<<<8, 256, 0, stream>>>(people, WgT, Hp);
    gemm_bt32<<<8, 256, 0, stream>>>(objects, WgT + 1024, HoF);

    // 5) p_graph assembly
    pgraph2<<<64, 256, 0, stream>>>(adjw, Hp, HoF, Yh, Zo, Wg_b, outG);
}

// Round 5
// 361.016 us; speedup vs baseline: 3.1747x; 3.1747x over previous
//
#include <hip/hip_runtime.h>

// VSGNet fused pipeline — fp32 in/out, bf16 MFMA compute.
// B=64 P=16 L=16 D=1024 SP=32 PROJ=512 ACT=29, C=16384.
// Factorizations: pairs@Wvis = Pp[b*16+p]+Po[b*16+l]+Pc[b];
// p_graph = people@Wg_p + adj@(oh@Wg_p) + objects@Wg_o [+ adjT@(ho@Wg_o), l>=1] + bg.
// R4 counters: relu_proj was 2x470us, latency-bound (30 blocks, 512 serial
// barriered k-steps each). R5: split over W1-column chunks (grid x16) with
// split-K atomicAdd into U; gemm_bt32 gets split-K too.

typedef unsigned short u16;   // bf16 bits
typedef short s16x8 __attribute__((ext_vector_type(8)));
typedef float f32x4 __attribute__((ext_vector_type(4)));

__device__ __forceinline__ u16 f2b(float f) {
    union { float f; unsigned int i; } v; v.f = f;
    unsigned int r = (v.i + 0x7fffu + ((v.i >> 16) & 1u)) >> 16;  // RNE
    return (u16)r;
}
__device__ __forceinline__ float b2f(u16 u) {
    union { float f; unsigned int i; } v; v.i = ((unsigned int)u) << 16; return v.f;
}
// load 8 consecutive fp32, convert to bf16 MFMA fragment
__device__ __forceinline__ s16x8 ld8(const float* p) {
    float4 a = *(const float4*)p;
    float4 b = *(const float4*)(p + 4);
    s16x8 r;
    r[0] = (short)f2b(a.x); r[1] = (short)f2b(a.y);
    r[2] = (short)f2b(a.z); r[3] = (short)f2b(a.w);
    r[4] = (short)f2b(b.x); r[5] = (short)f2b(b.y);
    r[6] = (short)f2b(b.z); r[7] = (short)f2b(b.w);
    return r;
}

// ---------------- workspace layout (bytes), total 2,973,696 ----------------
#define OFF_WSPATT 0u         // [512][32]  bf16
#define OFF_WREFT  32768u     // [32][512]  bf16 (rows 29..31 zero)
#define OFF_WATTT  65536u     // [32][512]  bf16
#define OFF_WGT    98304u     // [32][2048] bf16
#define OFF_PP     229376u    // [1024][512] bf16
#define OFF_PO     1277952u   // [1024][512] bf16
#define OFF_PC     2326528u   // [64][512]  bf16
#define OFF_ADJ    2392064u   // [16384] f32
#define OFF_HP     2457600u   // [1024][32] f32  people@Wg_p
#define OFF_HOF    2588672u   // [1024][32] f32  objects@Wg_o
#define OFF_YH     2719744u   // [1024][32] f32  relu(people@Who+b)@Wg_o
#define OFF_ZO     2850816u   // [960][32]  f32  relu(obj[:,1:]@Woh+b)@Wg_p
// HP..ZO contiguous f32 region zero-inited each launch (atomicAdd targets)
#define ZERO_OFF   2457600u
#define ZERO_LEN   516096u

// ---------------- small-weight transposes (fp32 src -> bf16 ws) -------------
__global__ __launch_bounds__(256) void transpose_small(
    const float* __restrict__ Wspat, const float* __restrict__ Wref,
    const float* __restrict__ Watt, const float* __restrict__ Wg,
    u16* __restrict__ WspatT, u16* __restrict__ WrefT,
    u16* __restrict__ WattT, u16* __restrict__ WgT)
{
    int g = blockIdx.x * 256 + threadIdx.x;
    int gsz = gridDim.x * 256;
    for (int i = g; i < 512 * 32; i += gsz) {          // WspatT[n][k] <- Wspat[k][n]
        int n = i >> 5, k = i & 31;
        WspatT[i] = f2b(Wspat[k * 512 + n]);
    }
    for (int i = g; i < 32 * 512; i += gsz) {          // WrefT[n][k] <- Wref[k][n<29]
        int n = i >> 9, k = i & 511;
        WrefT[i] = (n < 29) ? f2b(Wref[k * 29 + n]) : (u16)0;
    }
    for (int i = g; i < 32 * 512; i += gsz) {
        int n = i >> 9, k = i & 511;
        WattT[i] = (n < 29) ? f2b(Watt[k * 29 + n]) : (u16)0;
    }
    for (int i = g; i < 32 * 2048; i += gsz) {         // WgT[n][k] <- Wg[k][n<29]
        int n = i >> 11, k = i & 2047;
        WgT[i] = (n < 29) ? f2b(Wg[k * 29 + n]) : (u16)0;
    }
}

// ---- C[M,N] = A[M,K] @ W[K,N]. A,W fp32 (row-major); W LDS-transposed to bf16.
// Block tile 64x64, 4 waves 2x2 (each 32x32). Grid (N/64, M/64). K%32==0.
__global__ __launch_bounds__(256) void gemm_nt(
    const float* __restrict__ A, int lda,
    const float* __restrict__ W, int ldw,
    u16* __restrict__ outB, int ldo, int K)
{
    __shared__ u16 WT[64][40];   // [n_loc][k_loc], +8 pad
    int t = threadIdx.x;
    int lane = t & 63, w = t >> 6;
    int l16 = lane & 15, q = lane >> 4;
    int wy = w >> 1, wx = w & 1;
    int bm = blockIdx.y * 64 + wy * 32;
    int bn = blockIdx.x * 64;

    const float* ap0 = A + (size_t)(bm + l16) * lda + q * 8;
    const float* ap1 = A + (size_t)(bm + 16 + l16) * lda + q * 8;
    int kst = t >> 3;            // 0..31
    int nst = (t & 7) * 8;       // 0..56
    const float* wp = W + (size_t)kst * ldw + bn + nst;

    f32x4 acc00 = {0,0,0,0}, acc01 = {0,0,0,0}, acc10 = {0,0,0,0}, acc11 = {0,0,0,0};
    for (int k0 = 0; k0 < K; k0 += 32) {
        float4 w0 = *(const float4*)wp;
        float4 w1 = *(const float4*)(wp + 4);
        wp += (size_t)32 * ldw;
        __syncthreads();
        WT[nst + 0][kst] = f2b(w0.x); WT[nst + 1][kst] = f2b(w0.y);
        WT[nst + 2][kst] = f2b(w0.z); WT[nst + 3][kst] = f2b(w0.w);
        WT[nst + 4][kst] = f2b(w1.x); WT[nst + 5][kst] = f2b(w1.y);
        WT[nst + 6][kst] = f2b(w1.z); WT[nst + 7][kst] = f2b(w1.w);
        __syncthreads();
        s16x8 a0 = ld8(ap0); ap0 += 32;
        s16x8 a1 = ld8(ap1); ap1 += 32;
        s16x8 b0 = *(const s16x8*)(&WT[wx * 32 + l16][q * 8]);
        s16x8 b1 = *(const s16x8*)(&WT[wx * 32 + 16 + l16][q * 8]);
        acc00 = __builtin_amdgcn_mfma_f32_16x16x32_bf16(a0, b0, acc00, 0, 0, 0);
        acc01 = __builtin_amdgcn_mfma_f32_16x16x32_bf16(a0, b1, acc01, 0, 0, 0);
        acc10 = __builtin_amdgcn_mfma_f32_16x16x32_bf16(a1, b0, acc10, 0, 0, 0);
        acc11 = __builtin_amdgcn_mfma_f32_16x16x32_bf16(a1, b1, acc11, 0, 0, 0);
    }
    f32x4 accs[2][2] = {{acc00, acc01}, {acc10, acc11}};
#pragma unroll
    for (int ii = 0; ii < 2; ii++)
#pragma unroll
        for (int jj = 0; jj < 2; jj++) {
            int col = bn + wx * 32 + jj * 16 + l16;
#pragma unroll
            for (int r = 0; r < 4; r++) {
                int row = bm + ii * 16 + q * 4 + r;
                outB[(size_t)row * ldo + col] = f2b(accs[ii][jj][r]);
            }
        }
}

// ---- split relu-projection: U[32rows][32] += relu(A32@W1[:,nb:nb+64]+b1) @ Wg2[nb:nb+64,:]
// grid (rowTiles, 16). A,W1,b1 fp32; WgT2 bf16 [32 n][2048 k] (pre-offset).
// rowmap 1 = objects-skip-slot0. U accumulated via atomicAdd (pre-zeroed).
__global__ __launch_bounds__(256) void relu_proj_split(
    const float* __restrict__ A, int rowmap,
    const float* __restrict__ W1, const float* __restrict__ b1,
    const u16* __restrict__ WgT2, float* __restrict__ U)
{
    __shared__ u16 WT[64][40];   // W1 chunk, transposed [n_loc][k_loc]
    __shared__ u16 T[32][72];    // relu intermediate chunk (32 x 64), +8 pad
    int t = threadIdx.x;
    int lane = t & 63, w = t >> 6;
    int l16 = lane & 15, q = lane >> 4;
    int wy = w >> 1, wx = w & 1;
    int m0 = blockIdx.x * 32;
    int nb = blockIdx.y * 64;    // W1 column chunk == Wg2 k chunk

    int r = m0 + wy * 16 + l16;
    if (rowmap == 1) r = (r / 15) * 16 + (r % 15) + 1;
    const float* arow = A + (size_t)r * 1024;

    int kst = t >> 3, nst = (t & 7) * 8;
    const float* wp = W1 + (size_t)kst * 1024 + nb + nst;

    f32x4 acc0 = {0,0,0,0}, acc1 = {0,0,0,0};
    for (int k0 = 0; k0 < 1024; k0 += 32) {
        float4 w0 = *(const float4*)wp;
        float4 w1 = *(const float4*)(wp + 4);
        wp += 32 * 1024;
        __syncthreads();
        WT[nst + 0][kst] = f2b(w0.x); WT[nst + 1][kst] = f2b(w0.y);
        WT[nst + 2][kst] = f2b(w0.z); WT[nst + 3][kst] = f2b(w0.w);
        WT[nst + 4][kst] = f2b(w1.x); WT[nst + 5][kst] = f2b(w1.y);
        WT[nst + 6][kst] = f2b(w1.z); WT[nst + 7][kst] = f2b(w1.w);
        __syncthreads();
        s16x8 a = ld8(arow + k0 + q * 8);
        s16x8 b0 = *(const s16x8*)(&WT[wx * 32 + l16][q * 8]);
        s16x8 b1 = *(const s16x8*)(&WT[wx * 32 + 16 + l16][q * 8]);
        acc0 = __builtin_amdgcn_mfma_f32_16x16x32_bf16(a, b0, acc0, 0, 0, 0);
        acc1 = __builtin_amdgcn_mfma_f32_16x16x32_bf16(a, b1, acc1, 0, 0, 0);
    }
    // relu + bias -> T chunk (cols are partitioned across blocks: bias once)
#pragma unroll
    for (int jj = 0; jj < 2; jj++) {
        int col = wx * 32 + jj * 16 + l16;
        float bv = b1[nb + col];
#pragma unroll
        for (int rr = 0; rr < 4; rr++) {
            float v = (jj ? acc1[rr] : acc0[rr]) + bv;
            T[wy * 16 + q * 4 + rr][col] = f2b(fmaxf(v, 0.f));
        }
    }
    __syncthreads();

    // stage 2: U_part[32x32] = T(32x64) @ Wg2[nb:nb+64, :32]; wave w -> 16x16 tile
    int rt = w >> 1, ct = w & 1;
    f32x4 acc = {0,0,0,0};
#pragma unroll
    for (int kk = 0; kk < 64; kk += 32) {
        s16x8 a = *(const s16x8*)(&T[rt * 16 + l16][kk + q * 8]);
        s16x8 b = *(const s16x8*)(WgT2 + (size_t)(ct * 16 + l16) * 2048 + nb + kk + q * 8);
        acc = __builtin_amdgcn_mfma_f32_16x16x32_bf16(a, b, acc, 0, 0, 0);
    }
    int col = ct * 16 + l16;
#pragma unroll
    for (int rr = 0; rr < 4; rr++)
        atomicAdd(&U[(size_t)(m0 + rt * 16 + q * 4 + rr) * 32 + col], acc[rr]);
}

// ---- split-K: out[1024][32] += A[1024][1024]fp32 @ BT^T (BT [32][2048] bf16)
// grid (8, 4): 128 rows/block, 256-k chunk. out pre-zeroed, atomicAdd.
__global__ __launch_bounds__(256) void gemm_bt32_split(
    const float* __restrict__ A, const u16* __restrict__ BT,
    float* __restrict__ outF)
{
    int t = threadIdx.x, lane = t & 63, w = t >> 6;
    int l16 = lane & 15, q = lane >> 4;
    int bm = blockIdx.x * 128 + w * 32;
    int kb = blockIdx.y * 256;
    const float* ap0 = A + (size_t)(bm + l16) * 1024 + kb + q * 8;
    const float* ap1 = A + (size_t)(bm + 16 + l16) * 1024 + kb + q * 8;
    const u16* bp0 = BT + (size_t)l16 * 2048 + kb + q * 8;
    const u16* bp1 = BT + (size_t)(16 + l16) * 2048 + kb + q * 8;
    f32x4 acc00 = {0,0,0,0}, acc01 = {0,0,0,0}, acc10 = {0,0,0,0}, acc11 = {0,0,0,0};
    for (int k = 0; k < 256; k += 32) {
        s16x8 a0 = ld8(ap0); ap0 += 32;
        s16x8 a1 = ld8(ap1); ap1 += 32;
        s16x8 b0 = *(const s16x8*)bp0; bp0 += 32;
        s16x8 b1 = *(const s16x8*)bp1; bp1 += 32;
        acc00 = __builtin_amdgcn_mfma_f32_16x16x32_bf16(a0, b0, acc00, 0, 0, 0);
        acc01 = __builtin_amdgcn_mfma_f32_16x16x32_bf16(a0, b1, acc01, 0, 0, 0);
        acc10 = __builtin_amdgcn_mfma_f32_16x16x32_bf16(a1, b0, acc10, 0, 0, 0);
        acc11 = __builtin_amdgcn_mfma_f32_16x16x32_bf16(a1, b1, acc11, 0, 0, 0);
    }
    f32x4 accs[2][2] = {{acc00, acc01}, {acc10, acc11}};
#pragma unroll
    for (int ii = 0; ii < 2; ii++)
#pragma unroll
        for (int jj = 0; jj < 2; jj++)
#pragma unroll
            for (int r = 0; r < 4; r++)
                atomicAdd(&outF[(size_t)(bm + ii * 16 + q * 4 + r) * 32 + jj * 16 + l16],
                          accs[ii][jj][r]);
}

// ---- mega: per 32-row tile: aho(MFMA) -> p_att -> fref(in-place LDS)+i_ho -> p_ref
__global__ __launch_bounds__(256) void mega(
    const float* __restrict__ spatial, const u16* __restrict__ WspatT,
    const float* __restrict__ bspat,
    const u16* __restrict__ Pp, const u16* __restrict__ Po,
    const u16* __restrict__ Pc, const float* __restrict__ bvis,
    const u16* __restrict__ WrefT, const float* __restrict__ bref,
    const u16* __restrict__ WattT, const float* __restrict__ batt,
    const float* __restrict__ wip, const float* __restrict__ bip,
    float* __restrict__ outI, float* __restrict__ outRef,
    float* __restrict__ outAtt, float* __restrict__ adjw)
{
    __shared__ u16 tile[32][512];
    __shared__ float part[32][8];
    __shared__ float wipS[512];
    int t = threadIdx.x;
    int c0 = blockIdx.x * 32;
    int lane = t & 63, w = t >> 6;
    int l16 = lane & 15, q = lane >> 4;

    {
        float2 u = *(const float2*)(wip + t * 2);
        wipS[t * 2]     = u.x;
        wipS[t * 2 + 1] = u.y;
    }

    // step 1: aho rows c0..c0+31; wave w owns cols [w*128, w*128+128)
    {
        s16x8 a0 = ld8(spatial + (size_t)(c0 + l16) * 32 + q * 8);
        s16x8 a1 = ld8(spatial + (size_t)(c0 + 16 + l16) * 32 + q * 8);
#pragma unroll
        for (int nt = 0; nt < 8; nt++) {
            int n = w * 128 + nt * 16;
            s16x8 b = *(const s16x8*)(WspatT + (size_t)(n + l16) * 32 + q * 8);
            f32x4 acc0 = {0,0,0,0}, acc1 = {0,0,0,0};
            acc0 = __builtin_amdgcn_mfma_f32_16x16x32_bf16(a0, b, acc0, 0, 0, 0);
            acc1 = __builtin_amdgcn_mfma_f32_16x16x32_bf16(a1, b, acc1, 0, 0, 0);
            float bias = bspat[n + l16];
#pragma unroll
            for (int r = 0; r < 4; r++) {
                tile[q * 4 + r][n + l16]      = f2b(fmaxf(acc0[r] + bias, 0.f));
                tile[16 + q * 4 + r][n + l16] = f2b(fmaxf(acc1[r] + bias, 0.f));
            }
        }
    }
    __syncthreads();

    // step 2: p_att = aho @ WattT^T + batt
    {
        int rt = w >> 1, ct = w & 1;
        f32x4 acc = {0,0,0,0};
        for (int k = 0; k < 512; k += 32) {
            s16x8 a = *(const s16x8*)(&tile[rt * 16 + l16][k + q * 8]);
            s16x8 b = *(const s16x8*)(WattT + (size_t)(ct * 16 + l16) * 512 + k + q * 8);
            acc = __builtin_amdgcn_mfma_f32_16x16x32_bf16(a, b, acc, 0, 0, 0);
        }
        int col = ct * 16 + l16;
        if (col < 29) {
            float bias = batt[col];
#pragma unroll
            for (int r = 0; r < 4; r++) {
                int row = c0 + rt * 16 + q * 4 + r;
                outAtt[(size_t)row * 29 + col] = acc[r] + bias;
            }
        }
    }
    __syncthreads();   // all reads of aho done before in-place overwrite

    // step 3: fref = relu(Pp+Po+Pc+bvis) * aho (in-place); i_ho partials
    {
        int row = t >> 3, g = t & 7;
        int c = c0 + row;
        int rp = c >> 4, bimg = c >> 8;
        int ro = bimg * 16 + (c & 15);
        const u16* ppr = Pp + (size_t)rp * 512;
        const u16* por = Po + (size_t)ro * 512;
        const u16* pcr = Pc + (size_t)bimg * 512;
        float ps = 0.f;
#pragma unroll 4
        for (int j = 0; j < 64; j += 2) {
            int col = g * 64 + j;
            unsigned int upp = *(const unsigned int*)(ppr + col);
            unsigned int upo = *(const unsigned int*)(por + col);
            unsigned int upc = *(const unsigned int*)(pcr + col);
            float2 bv = *(const float2*)(bvis + col);
            unsigned int uah = *(const unsigned int*)(&tile[row][col]);
            float fv0 = fmaxf(b2f((u16)(upp & 0xffff)) + b2f((u16)(upo & 0xffff))
                            + b2f((u16)(upc & 0xffff)) + bv.x, 0.f);
            float fv1 = fmaxf(b2f((u16)(upp >> 16)) + b2f((u16)(upo >> 16))
                            + b2f((u16)(upc >> 16)) + bv.y, 0.f);
            float fr0 = fv0 * b2f((u16)(uah & 0xffff));
            float fr1 = fv1 * b2f((u16)(uah >> 16));
            *(unsigned int*)(&tile[row][col]) =
                (unsigned int)f2b(fr0) | ((unsigned int)f2b(fr1) << 16);
            ps += fr0 * wipS[col] + fr1 * wipS[col + 1];
        }
        part[row][g] = ps;
    }
    __syncthreads();

    if (t < 32) {
        float s = part[t][0] + part[t][1] + part[t][2] + part[t][3]
                + part[t][4] + part[t][5] + part[t][6] + part[t][7] + bip[0];
        outI[c0 + t] = s;
        adjw[c0 + t] = 1.f / (1.f + expf(-s));
    }

    // step 4: p_ref = fref @ WrefT^T + bref
    {
        int rt = w >> 1, ct = w & 1;
        f32x4 acc = {0,0,0,0};
        for (int k = 0; k < 512; k += 32) {
            s16x8 a = *(const s16x8*)(&tile[rt * 16 + l16][k + q * 8]);
            s16x8 b = *(const s16x8*)(WrefT + (size_t)(ct * 16 + l16) * 512 + k + q * 8);
            acc = __builtin_amdgcn_mfma_f32_16x16x32_bf16(a, b, acc, 0, 0, 0);
        }
        int col = ct * 16 + l16;
        if (col < 29) {
            float bias = bref[col];
#pragma unroll
            for (int r = 0; r < 4; r++) {
                int row = c0 + rt * 16 + q * 4 + r;
                outRef[(size_t)row * 29 + col] = acc[r] + bias;
            }
        }
    }
}

// ---- p_graph: per image, tiny adj contractions + broadcast sum -------------
__global__ __launch_bounds__(256) void pgraph2(
    const float* __restrict__ adjw, const float* __restrict__ Hp,
    const float* __restrict__ HoF, const float* __restrict__ Yh,
    const float* __restrict__ Zo, const float* __restrict__ bg,
    float* __restrict__ outG)
{
    int b = blockIdx.x, t = threadIdx.x;
    __shared__ float adjS[16][16];
    __shared__ float YhS[16][32];
    __shared__ float ZoS[15][32];
    __shared__ float PA[16][32];
    __shared__ float OA[16][32];
    adjS[t >> 4][t & 15] = adjw[b * 256 + t];
    for (int i = t; i < 512; i += 256)
        YhS[i >> 5][i & 31] = Yh[(size_t)(b * 16 + (i >> 5)) * 32 + (i & 31)];
    for (int i = t; i < 480; i += 256)
        ZoS[i >> 5][i & 31] = Zo[(size_t)(b * 15 + (i >> 5)) * 32 + (i & 31)];
    __syncthreads();
    for (int i = t; i < 512; i += 256) {
        int p = i >> 5, j = i & 31;
        float s = 0.f;
#pragma unroll
        for (int o = 0; o < 15; o++) s += adjS[p][o + 1] * ZoS[o][j];
        PA[p][j] = s;
        float s2 = 0.f;
#pragma unroll
        for (int pp = 0; pp < 16; pp++) s2 += adjS[pp][p] * YhS[pp][j];
        OA[p][j] = s2;          // valid for slot index >=1; [0] unused
    }
    __syncthreads();
    int p = t >> 4, l = t & 15;
    const float* hp = Hp + (size_t)(b * 16 + p) * 32;
    const float* ho = HoF + (size_t)(b * 16 + l) * 32;
    size_t c = (size_t)b * 256 + t;
    for (int j = 0; j < 29; j++) {
        float v = hp[j] + ho[j] + bg[j] + PA[p][j];
        if (l >= 1) v += OA[l][j];
        outG[c * 29 + j] = v;
    }
}

extern "C" void kernel_launch(void* const* d_in, const int* in_sizes, int n_in,
                              void* d_out, int out_size, void* d_ws, size_t ws_size,
                              hipStream_t stream)
{
    const float* people  = (const float*)d_in[0];
    const float* objects = (const float*)d_in[1];
    const float* context = (const float*)d_in[2];
    const float* spatial = (const float*)d_in[3];
    const float* Wvis_w  = (const float*)d_in[4];
    const float* Wvis_b  = (const float*)d_in[5];
    const float* Wspat_w = (const float*)d_in[6];
    const float* Wspat_b = (const float*)d_in[7];
    const float* Wip_w   = (const float*)d_in[8];
    const float* Wip_b   = (const float*)d_in[9];
    const float* Wref_w  = (const float*)d_in[10];
    const float* Wref_b  = (const float*)d_in[11];
    const float* Watt_w  = (const float*)d_in[12];
    const float* Watt_b  = (const float*)d_in[13];
    const float* Woh_w   = (const float*)d_in[14];
    const float* Woh_b   = (const float*)d_in[15];
    const float* Who_w   = (const float*)d_in[16];
    const float* Who_b   = (const float*)d_in[17];
    const float* Wg_w    = (const float*)d_in[18];
    const float* Wg_b    = (const float*)d_in[19];

    char* ws = (char*)d_ws;
    u16* WspatT = (u16*)(ws + OFF_WSPATT);
    u16* WrefT  = (u16*)(ws + OFF_WREFT);
    u16* WattT  = (u16*)(ws + OFF_WATTT);
    u16* WgT    = (u16*)(ws + OFF_WGT);
    u16* Ppb    = (u16*)(ws + OFF_PP);
    u16* Pob    = (u16*)(ws + OFF_PO);
    u16* Pcb    = (u16*)(ws + OFF_PC);
    float* adjw = (float*)(ws + OFF_ADJ);
    float* Hp   = (float*)(ws + OFF_HP);
    float* HoF  = (float*)(ws + OFF_HOF);
    float* Yh   = (float*)(ws + OFF_YH);
    float* Zo   = (float*)(ws + OFF_ZO);

    float* outI   = (float*)d_out;        // i_ho   [16384]
    float* outRef = outI + 16384;         // p_ref  [16384,29]
    float* outAtt = outI + 491520;        // p_att  [16384,29]
    float* outG   = outI + 966656;        // p_graph[16384,29]

    // 0) zero the atomic accumulation region (Hp/HoF/Yh/Zo)
    hipMemsetAsync(ws + ZERO_OFF, 0, ZERO_LEN, stream);

    // 1) small-weight transposes (224 KB bf16)
    transpose_small<<<256, 256, 0, stream>>>(Wspat_w, Wref_w, Watt_w, Wg_w,
                                             WspatT, WrefT, WattT, WgT);

    // 2) Pp/Po/Pc = {people,objects,context} @ Wvis slices (LDS-transposed W)
    gemm_nt<<<dim3(8, 16), 256, 0, stream>>>(people, 1024,
        Wvis_w, 512, Ppb, 512, 1024);
    gemm_nt<<<dim3(8, 16), 256, 0, stream>>>(objects, 1024,
        Wvis_w + (size_t)1024 * 512, 512, Pob, 512, 1024);
    gemm_nt<<<dim3(8, 1), 256, 0, stream>>>(context, 1024,
        Wvis_w + (size_t)2048 * 512, 512, Pcb, 512, 1024);

    // 3) fused aho / p_att / fref / i_ho / p_ref
    mega<<<512, 256, 0, stream>>>(spatial, WspatT, Wspat_b,
                                  Ppb, Pob, Pcb, Wvis_b,
                                  WrefT, Wref_b, WattT, Watt_b,
                                  Wip_w, Wip_b,
                                  outI, outRef, outAtt, adjw);

    // 4) graph-head projections, split over W1 columns (x16 parallelism)
    relu_proj_split<<<dim3(32, 16), 256, 0, stream>>>(people, 0, Who_w, Who_b,
                                                      WgT + 1024, Yh);
    relu_proj_split<<<dim3(30, 16), 256, 0, stream>>>(objects, 1, Woh_w, Woh_b,
                                                      WgT, Zo);
    gemm_bt32_split<<<dim3(8, 4), 256, 0, stream>>>(people, WgT, Hp);
    gemm_bt32_split<<<dim3(8, 4), 256, 0, stream>>>(objects, WgT + 1024, HoF);

    // 5) p_graph assembly
    pgraph2<<<64, 256, 0, stream>>>(adjw, Hp, HoF, Yh, Zo, Wg_b, outG);
}

// Round 6
// 230.541 us; speedup vs baseline: 4.9715x; 1.5660x over previous
//
#include <hip/hip_runtime.h>

// VSGNet fused pipeline — fp32 in/out, bf16 MFMA compute.
// B=64 P=16 L=16 D=1024 SP=32 PROJ=512 ACT=29, C=16384.
// Factorizations: pairs@Wvis = Pp[b*16+p]+Po[b*16+l]+Pc[b];
// p_graph = people@Wg_p + adj@(oh@Wg_p) + objects@Wg_o [+ adjT@(ho@Wg_o), l>=1] + bg.
// R5 counters: gemm_nt 3x60us latency-bound (LDS-transpose double-barrier k-loop,
// 0.5 blocks/CU). R6: barrier-free GEMMs — B-fragments built via strided dword
// loads from row-major W (no LDS), 3 Wvis GEMMs batched in one launch; same
// treatment for relu_proj stage 1; relu_proj/gemm_bt32 pairs batched via grid.z.

typedef unsigned short u16;   // bf16 bits
typedef short s16x8 __attribute__((ext_vector_type(8)));
typedef float f32x4 __attribute__((ext_vector_type(4)));

__device__ __forceinline__ u16 f2b(float f) {
    union { float f; unsigned int i; } v; v.f = f;
    unsigned int r = (v.i + 0x7fffu + ((v.i >> 16) & 1u)) >> 16;  // RNE
    return (u16)r;
}
__device__ __forceinline__ float b2f(u16 u) {
    union { float f; unsigned int i; } v; v.i = ((unsigned int)u) << 16; return v.f;
}
// load 8 consecutive fp32, convert to bf16 MFMA fragment
__device__ __forceinline__ s16x8 ld8(const float* p) {
    float4 a = *(const float4*)p;
    float4 b = *(const float4*)(p + 4);
    s16x8 r;
    r[0] = (short)f2b(a.x); r[1] = (short)f2b(a.y);
    r[2] = (short)f2b(a.z); r[3] = (short)f2b(a.w);
    r[4] = (short)f2b(b.x); r[5] = (short)f2b(b.y);
    r[6] = (short)f2b(b.z); r[7] = (short)f2b(b.w);
    return r;
}
// build B-fragment from row-major W[k][n]: lane col fixed, 8 strided k loads
__device__ __forceinline__ s16x8 ldb(const float* p, int ldw) {
    s16x8 r;
#pragma unroll
    for (int j = 0; j < 8; j++) r[j] = (short)f2b(p[(size_t)j * ldw]);
    return r;
}

// ---------------- workspace layout (bytes), total 2,973,696 ----------------
#define OFF_WSPATT 0u         // [512][32]  bf16
#define OFF_WREFT  32768u     // [32][512]  bf16 (rows 29..31 zero)
#define OFF_WATTT  65536u     // [32][512]  bf16
#define OFF_WGT    98304u     // [32][2048] bf16
#define OFF_PP     229376u    // [1024][512] bf16
#define OFF_PO     1277952u   // [1024][512] bf16
#define OFF_PC     2326528u   // [64][512]  bf16
#define OFF_ADJ    2392064u   // [16384] f32
#define OFF_HP     2457600u   // [1024][32] f32  people@Wg_p
#define OFF_HOF    2588672u   // [1024][32] f32  objects@Wg_o
#define OFF_YH     2719744u   // [1024][32] f32  relu(people@Who+b)@Wg_o
#define OFF_ZO     2850816u   // [960][32]  f32  relu(obj[:,1:]@Woh+b)@Wg_p
#define ZERO_OFF   2457600u
#define ZERO_LEN   516096u

// ---------------- small-weight transposes (fp32 src -> bf16 ws) -------------
__global__ __launch_bounds__(256) void transpose_small(
    const float* __restrict__ Wspat, const float* __restrict__ Wref,
    const float* __restrict__ Watt, const float* __restrict__ Wg,
    u16* __restrict__ WspatT, u16* __restrict__ WrefT,
    u16* __restrict__ WattT, u16* __restrict__ WgT)
{
    int g = blockIdx.x * 256 + threadIdx.x;
    int gsz = gridDim.x * 256;
    for (int i = g; i < 512 * 32; i += gsz) {          // WspatT[n][k] <- Wspat[k][n]
        int n = i >> 5, k = i & 31;
        WspatT[i] = f2b(Wspat[k * 512 + n]);
    }
    for (int i = g; i < 32 * 512; i += gsz) {          // WrefT[n][k] <- Wref[k][n<29]
        int n = i >> 9, k = i & 511;
        WrefT[i] = (n < 29) ? f2b(Wref[k * 29 + n]) : (u16)0;
    }
    for (int i = g; i < 32 * 512; i += gsz) {
        int n = i >> 9, k = i & 511;
        WattT[i] = (n < 29) ? f2b(Watt[k * 29 + n]) : (u16)0;
    }
    for (int i = g; i < 32 * 2048; i += gsz) {         // WgT[n][k] <- Wg[k][n<29]
        int n = i >> 11, k = i & 2047;
        WgT[i] = (n < 29) ? f2b(Wg[k * 29 + n]) : (u16)0;
    }
}

// ---- batched barrier-free GEMM: {Pp,Po,Pc} = {people,objects,context} @ Wvis
// slices. grid (8, 33): y<16 people, y<32 objects, y==32 context. Block tile
// 64x64, 4 waves 2x2. B-frags via strided dword loads (no LDS, no barriers).
__global__ __launch_bounds__(256) void gemm3(
    const float* __restrict__ people, const float* __restrict__ objects,
    const float* __restrict__ context, const float* __restrict__ Wvis,
    u16* __restrict__ Pp, u16* __restrict__ Po, u16* __restrict__ Pc)
{
    int t = threadIdx.x;
    int lane = t & 63, w = t >> 6;
    int l16 = lane & 15, q = lane >> 4;
    int wy = w >> 1, wx = w & 1;
    int ty = blockIdx.y;
    const float* A; u16* outB; const float* W; int bm;
    if (ty < 16)      { A = people;  outB = Pp; W = Wvis;                      bm = ty * 64; }
    else if (ty < 32) { A = objects; outB = Po; W = Wvis + (size_t)1024 * 512; bm = (ty - 16) * 64; }
    else              { A = context; outB = Pc; W = Wvis + (size_t)2048 * 512; bm = 0; }
    int bn = blockIdx.x * 64;

    const float* ap0 = A + (size_t)(bm + wy * 32 + l16) * 1024 + q * 8;
    const float* ap1 = ap0 + (size_t)16 * 1024;
    const float* wp0 = W + (size_t)(q * 8) * 512 + bn + wx * 32 + l16;
    const float* wp1 = wp0 + 16;

    f32x4 acc00 = {0,0,0,0}, acc01 = {0,0,0,0}, acc10 = {0,0,0,0}, acc11 = {0,0,0,0};
    for (int k0 = 0; k0 < 1024; k0 += 32) {
        s16x8 a0 = ld8(ap0); ap0 += 32;
        s16x8 a1 = ld8(ap1); ap1 += 32;
        s16x8 b0 = ldb(wp0, 512); wp0 += (size_t)32 * 512;
        s16x8 b1 = ldb(wp1, 512); wp1 += (size_t)32 * 512;
        acc00 = __builtin_amdgcn_mfma_f32_16x16x32_bf16(a0, b0, acc00, 0, 0, 0);
        acc01 = __builtin_amdgcn_mfma_f32_16x16x32_bf16(a0, b1, acc01, 0, 0, 0);
        acc10 = __builtin_amdgcn_mfma_f32_16x16x32_bf16(a1, b0, acc10, 0, 0, 0);
        acc11 = __builtin_amdgcn_mfma_f32_16x16x32_bf16(a1, b1, acc11, 0, 0, 0);
    }
    f32x4 accs[2][2] = {{acc00, acc01}, {acc10, acc11}};
#pragma unroll
    for (int ii = 0; ii < 2; ii++)
#pragma unroll
        for (int jj = 0; jj < 2; jj++) {
            int col = bn + wx * 32 + jj * 16 + l16;
#pragma unroll
            for (int r = 0; r < 4; r++) {
                int row = bm + wy * 32 + ii * 16 + q * 4 + r;
                outB[(size_t)row * 512 + col] = f2b(accs[ii][jj][r]);
            }
        }
}

// ---- batched split relu-projection (barrier-free stage 1):
// z=0: Yh += relu(people@Who[:,nb:+64]+b)@WgT_o[nb:+64,:]
// z=1: Zo += relu(objects[skip0]@Woh[:,nb:+64]+b)@WgT_p[nb:+64,:]
// grid (32, 16, 2). U accumulated via atomicAdd (pre-zeroed).
__global__ __launch_bounds__(256) void relu_proj2(
    const float* __restrict__ people, const float* __restrict__ objects,
    const float* __restrict__ Who, const float* __restrict__ Who_b,
    const float* __restrict__ Woh, const float* __restrict__ Woh_b,
    const u16* __restrict__ WgT,
    float* __restrict__ Yh, float* __restrict__ Zo)
{
    __shared__ u16 T[32][72];    // relu intermediate chunk (32 x 64), +8 pad
    int z = blockIdx.z;
    int m0 = blockIdx.x * 32;
    if (z && m0 >= 960) return;
    const float* A  = z ? objects : people;
    const float* W1 = z ? Woh : Who;
    const float* bb = z ? Woh_b : Who_b;
    const u16* Wg2  = z ? WgT : WgT + 1024;
    float* U        = z ? Zo : Yh;

    int t = threadIdx.x;
    int lane = t & 63, w = t >> 6;
    int l16 = lane & 15, q = lane >> 4;
    int wy = w >> 1, wx = w & 1;
    int nb = blockIdx.y * 64;

    int r = m0 + wy * 16 + l16;
    if (z) r = (r / 15) * 16 + (r % 15) + 1;
    const float* arow = A + (size_t)r * 1024;
    const float* wp0 = W1 + (size_t)(q * 8) * 1024 + nb + wx * 32 + l16;
    const float* wp1 = wp0 + 16;

    f32x4 acc0 = {0,0,0,0}, acc1 = {0,0,0,0};
    for (int k0 = 0; k0 < 1024; k0 += 32) {
        s16x8 a = ld8(arow + k0 + q * 8);
        s16x8 b0 = ldb(wp0, 1024); wp0 += (size_t)32 * 1024;
        s16x8 b1 = ldb(wp1, 1024); wp1 += (size_t)32 * 1024;
        acc0 = __builtin_amdgcn_mfma_f32_16x16x32_bf16(a, b0, acc0, 0, 0, 0);
        acc1 = __builtin_amdgcn_mfma_f32_16x16x32_bf16(a, b1, acc1, 0, 0, 0);
    }
    // relu + bias -> T chunk (cols partitioned across nb-blocks: bias once)
#pragma unroll
    for (int jj = 0; jj < 2; jj++) {
        int col = wx * 32 + jj * 16 + l16;
        float bv = bb[nb + col];
#pragma unroll
        for (int rr = 0; rr < 4; rr++) {
            float v = (jj ? acc1[rr] : acc0[rr]) + bv;
            T[wy * 16 + q * 4 + rr][col] = f2b(fmaxf(v, 0.f));
        }
    }
    __syncthreads();

    // stage 2: U_part[32x32] = T(32x64) @ Wg2[nb:nb+64, :32]
    int rt = w >> 1, ct = w & 1;
    f32x4 acc = {0,0,0,0};
#pragma unroll
    for (int kk = 0; kk < 64; kk += 32) {
        s16x8 a = *(const s16x8*)(&T[rt * 16 + l16][kk + q * 8]);
        s16x8 b = *(const s16x8*)(Wg2 + (size_t)(ct * 16 + l16) * 2048 + nb + kk + q * 8);
        acc = __builtin_amdgcn_mfma_f32_16x16x32_bf16(a, b, acc, 0, 0, 0);
    }
    int col = ct * 16 + l16;
#pragma unroll
    for (int rr = 0; rr < 4; rr++)
        atomicAdd(&U[(size_t)(m0 + rt * 16 + q * 4 + rr) * 32 + col], acc[rr]);
}

// ---- batched split-K: z=0 Hp += people@WgT_p^T; z=1 HoF += objects@WgT_o^T
// grid (8, 8, 2): 128 rows/block, 128-k chunk. out pre-zeroed, atomicAdd.
__global__ __launch_bounds__(256) void gemm_bt32b(
    const float* __restrict__ people, const float* __restrict__ objects,
    const u16* __restrict__ WgT, float* __restrict__ Hp, float* __restrict__ HoF)
{
    int z = blockIdx.z;
    const float* A = z ? objects : people;
    const u16* BT  = z ? WgT + 1024 : WgT;
    float* outF    = z ? HoF : Hp;
    int t = threadIdx.x, lane = t & 63, w = t >> 6;
    int l16 = lane & 15, q = lane >> 4;
    int bm = blockIdx.x * 128 + w * 32;
    int kb = blockIdx.y * 128;
    const float* ap0 = A + (size_t)(bm + l16) * 1024 + kb + q * 8;
    const float* ap1 = A + (size_t)(bm + 16 + l16) * 1024 + kb + q * 8;
    const u16* bp0 = BT + (size_t)l16 * 2048 + kb + q * 8;
    const u16* bp1 = BT + (size_t)(16 + l16) * 2048 + kb + q * 8;
    f32x4 acc00 = {0,0,0,0}, acc01 = {0,0,0,0}, acc10 = {0,0,0,0}, acc11 = {0,0,0,0};
    for (int k = 0; k < 128; k += 32) {
        s16x8 a0 = ld8(ap0); ap0 += 32;
        s16x8 a1 = ld8(ap1); ap1 += 32;
        s16x8 b0 = *(const s16x8*)bp0; bp0 += 32;
        s16x8 b1 = *(const s16x8*)bp1; bp1 += 32;
        acc00 = __builtin_amdgcn_mfma_f32_16x16x32_bf16(a0, b0, acc00, 0, 0, 0);
        acc01 = __builtin_amdgcn_mfma_f32_16x16x32_bf16(a0, b1, acc01, 0, 0, 0);
        acc10 = __builtin_amdgcn_mfma_f32_16x16x32_bf16(a1, b0, acc10, 0, 0, 0);
        acc11 = __builtin_amdgcn_mfma_f32_16x16x32_bf16(a1, b1, acc11, 0, 0, 0);
    }
    f32x4 accs[2][2] = {{acc00, acc01}, {acc10, acc11}};
#pragma unroll
    for (int ii = 0; ii < 2; ii++)
#pragma unroll
        for (int jj = 0; jj < 2; jj++)
#pragma unroll
            for (int r = 0; r < 4; r++)
                atomicAdd(&outF[(size_t)(bm + ii * 16 + q * 4 + r) * 32 + jj * 16 + l16],
                          accs[ii][jj][r]);
}

// ---- mega: per 32-row tile: aho(MFMA) -> p_att -> fref(in-place LDS)+i_ho -> p_ref
__global__ __launch_bounds__(256) void mega(
    const float* __restrict__ spatial, const u16* __restrict__ WspatT,
    const float* __restrict__ bspat,
    const u16* __restrict__ Pp, const u16* __restrict__ Po,
    const u16* __restrict__ Pc, const float* __restrict__ bvis,
    const u16* __restrict__ WrefT, const float* __restrict__ bref,
    const u16* __restrict__ WattT, const float* __restrict__ batt,
    const float* __restrict__ wip, const float* __restrict__ bip,
    float* __restrict__ outI, float* __restrict__ outRef,
    float* __restrict__ outAtt, float* __restrict__ adjw)
{
    __shared__ u16 tile[32][512];
    __shared__ float part[32][8];
    __shared__ float wipS[512];
    int t = threadIdx.x;
    int c0 = blockIdx.x * 32;
    int lane = t & 63, w = t >> 6;
    int l16 = lane & 15, q = lane >> 4;

    {
        float2 u = *(const float2*)(wip + t * 2);
        wipS[t * 2]     = u.x;
        wipS[t * 2 + 1] = u.y;
    }

    // step 1: aho rows c0..c0+31; wave w owns cols [w*128, w*128+128)
    {
        s16x8 a0 = ld8(spatial + (size_t)(c0 + l16) * 32 + q * 8);
        s16x8 a1 = ld8(spatial + (size_t)(c0 + 16 + l16) * 32 + q * 8);
#pragma unroll
        for (int nt = 0; nt < 8; nt++) {
            int n = w * 128 + nt * 16;
            s16x8 b = *(const s16x8*)(WspatT + (size_t)(n + l16) * 32 + q * 8);
            f32x4 acc0 = {0,0,0,0}, acc1 = {0,0,0,0};
            acc0 = __builtin_amdgcn_mfma_f32_16x16x32_bf16(a0, b, acc0, 0, 0, 0);
            acc1 = __builtin_amdgcn_mfma_f32_16x16x32_bf16(a1, b, acc1, 0, 0, 0);
            float bias = bspat[n + l16];
#pragma unroll
            for (int r = 0; r < 4; r++) {
                tile[q * 4 + r][n + l16]      = f2b(fmaxf(acc0[r] + bias, 0.f));
                tile[16 + q * 4 + r][n + l16] = f2b(fmaxf(acc1[r] + bias, 0.f));
            }
        }
    }
    __syncthreads();

    // step 2: p_att = aho @ WattT^T + batt
    {
        int rt = w >> 1, ct = w & 1;
        f32x4 acc = {0,0,0,0};
        for (int k = 0; k < 512; k += 32) {
            s16x8 a = *(const s16x8*)(&tile[rt * 16 + l16][k + q * 8]);
            s16x8 b = *(const s16x8*)(WattT + (size_t)(ct * 16 + l16) * 512 + k + q * 8);
            acc = __builtin_amdgcn_mfma_f32_16x16x32_bf16(a, b, acc, 0, 0, 0);
        }
        int col = ct * 16 + l16;
        if (col < 29) {
            float bias = batt[col];
#pragma unroll
            for (int r = 0; r < 4; r++) {
                int row = c0 + rt * 16 + q * 4 + r;
                outAtt[(size_t)row * 29 + col] = acc[r] + bias;
            }
        }
    }
    __syncthreads();   // all reads of aho done before in-place overwrite

    // step 3: fref = relu(Pp+Po+Pc+bvis) * aho (in-place); i_ho partials
    {
        int row = t >> 3, g = t & 7;
        int c = c0 + row;
        int rp = c >> 4, bimg = c >> 8;
        int ro = bimg * 16 + (c & 15);
        const u16* ppr = Pp + (size_t)rp * 512;
        const u16* por = Po + (size_t)ro * 512;
        const u16* pcr = Pc + (size_t)bimg * 512;
        float ps = 0.f;
#pragma unroll 4
        for (int j = 0; j < 64; j += 2) {
            int col = g * 64 + j;
            unsigned int upp = *(const unsigned int*)(ppr + col);
            unsigned int upo = *(const unsigned int*)(por + col);
            unsigned int upc = *(const unsigned int*)(pcr + col);
            float2 bv = *(const float2*)(bvis + col);
            unsigned int uah = *(const unsigned int*)(&tile[row][col]);
            float fv0 = fmaxf(b2f((u16)(upp & 0xffff)) + b2f((u16)(upo & 0xffff))
                            + b2f((u16)(upc & 0xffff)) + bv.x, 0.f);
            float fv1 = fmaxf(b2f((u16)(upp >> 16)) + b2f((u16)(upo >> 16))
                            + b2f((u16)(upc >> 16)) + bv.y, 0.f);
            float fr0 = fv0 * b2f((u16)(uah & 0xffff));
            float fr1 = fv1 * b2f((u16)(uah >> 16));
            *(unsigned int*)(&tile[row][col]) =
                (unsigned int)f2b(fr0) | ((unsigned int)f2b(fr1) << 16);
            ps += fr0 * wipS[col] + fr1 * wipS[col + 1];
        }
        part[row][g] = ps;
    }
    __syncthreads();

    if (t < 32) {
        float s = part[t][0] + part[t][1] + part[t][2] + part[t][3]
                + part[t][4] + part[t][5] + part[t][6] + part[t][7] + bip[0];
        outI[c0 + t] = s;
        adjw[c0 + t] = 1.f / (1.f + expf(-s));
    }

    // step 4: p_ref = fref @ WrefT^T + bref
    {
        int rt = w >> 1, ct = w & 1;
        f32x4 acc = {0,0,0,0};
        for (int k = 0; k < 512; k += 32) {
            s16x8 a = *(const s16x8*)(&tile[rt * 16 + l16][k + q * 8]);
            s16x8 b = *(const s16x8*)(WrefT + (size_t)(ct * 16 + l16) * 512 + k + q * 8);
            acc = __builtin_amdgcn_mfma_f32_16x16x32_bf16(a, b, acc, 0, 0, 0);
        }
        int col = ct * 16 + l16;
        if (col < 29) {
            float bias = bref[col];
#pragma unroll
            for (int r = 0; r < 4; r++) {
                int row = c0 + rt * 16 + q * 4 + r;
                outRef[(size_t)row * 29 + col] = acc[r] + bias;
            }
        }
    }
}

// ---- p_graph: per image, tiny adj contractions + broadcast sum -------------
__global__ __launch_bounds__(256) void pgraph2(
    const float* __restrict__ adjw, const float* __restrict__ Hp,
    const float* __restrict__ HoF, const float* __restrict__ Yh,
    const float* __restrict__ Zo, const float* __restrict__ bg,
    float* __restrict__ outG)
{
    int b = blockIdx.x, t = threadIdx.x;
    __shared__ float adjS[16][16];
    __shared__ float YhS[16][32];
    __shared__ float ZoS[15][32];
    __shared__ float PA[16][32];
    __shared__ float OA[16][32];
    adjS[t >> 4][t & 15] = adjw[b * 256 + t];
    for (int i = t; i < 512; i += 256)
        YhS[i >> 5][i & 31] = Yh[(size_t)(b * 16 + (i >> 5)) * 32 + (i & 31)];
    for (int i = t; i < 480; i += 256)
        ZoS[i >> 5][i & 31] = Zo[(size_t)(b * 15 + (i >> 5)) * 32 + (i & 31)];
    __syncthreads();
    for (int i = t; i < 512; i += 256) {
        int p = i >> 5, j = i & 31;
        float s = 0.f;
#pragma unroll
        for (int o = 0; o < 15; o++) s += adjS[p][o + 1] * ZoS[o][j];
        PA[p][j] = s;
        float s2 = 0.f;
#pragma unroll
        for (int pp = 0; pp < 16; pp++) s2 += adjS[pp][p] * YhS[pp][j];
        OA[p][j] = s2;          // valid for slot index >=1; [0] unused
    }
    __syncthreads();
    int p = t >> 4, l = t & 15;
    const float* hp = Hp + (size_t)(b * 16 + p) * 32;
    const float* ho = HoF + (size_t)(b * 16 + l) * 32;
    size_t c = (size_t)b * 256 + t;
    for (int j = 0; j < 29; j++) {
        float v = hp[j] + ho[j] + bg[j] + PA[p][j];
        if (l >= 1) v += OA[l][j];
        outG[c * 29 + j] = v;
    }
}

extern "C" void kernel_launch(void* const* d_in, const int* in_sizes, int n_in,
                              void* d_out, int out_size, void* d_ws, size_t ws_size,
                              hipStream_t stream)
{
    const float* people  = (const float*)d_in[0];
    const float* objects = (const float*)d_in[1];
    const float* context = (const float*)d_in[2];
    const float* spatial = (const float*)d_in[3];
    const float* Wvis_w  = (const float*)d_in[4];
    const float* Wvis_b  = (const float*)d_in[5];
    const float* Wspat_w = (const float*)d_in[6];
    const float* Wspat_b = (const float*)d_in[7];
    const float* Wip_w   = (const float*)d_in[8];
    const float* Wip_b   = (const float*)d_in[9];
    const float* Wref_w  = (const float*)d_in[10];
    const float* Wref_b  = (const float*)d_in[11];
    const float* Watt_w  = (const float*)d_in[12];
    const float* Watt_b  = (const float*)d_in[13];
    const float* Woh_w   = (const float*)d_in[14];
    const float* Woh_b   = (const float*)d_in[15];
    const float* Who_w   = (const float*)d_in[16];
    const float* Who_b   = (const float*)d_in[17];
    const float* Wg_w    = (const float*)d_in[18];
    const float* Wg_b    = (const float*)d_in[19];

    char* ws = (char*)d_ws;
    u16* WspatT = (u16*)(ws + OFF_WSPATT);
    u16* WrefT  = (u16*)(ws + OFF_WREFT);
    u16* WattT  = (u16*)(ws + OFF_WATTT);
    u16* WgT    = (u16*)(ws + OFF_WGT);
    u16* Ppb    = (u16*)(ws + OFF_PP);
    u16* Pob    = (u16*)(ws + OFF_PO);
    u16* Pcb    = (u16*)(ws + OFF_PC);
    float* adjw = (float*)(ws + OFF_ADJ);
    float* Hp   = (float*)(ws + OFF_HP);
    float* HoF  = (float*)(ws + OFF_HOF);
    float* Yh   = (float*)(ws + OFF_YH);
    float* Zo   = (float*)(ws + OFF_ZO);

    float* outI   = (float*)d_out;        // i_ho   [16384]
    float* outRef = outI + 16384;         // p_ref  [16384,29]
    float* outAtt = outI + 491520;        // p_att  [16384,29]
    float* outG   = outI + 966656;        // p_graph[16384,29]

    // 0) zero the atomic accumulation region (Hp/HoF/Yh/Zo)
    hipMemsetAsync(ws + ZERO_OFF, 0, ZERO_LEN, stream);

    // 1) small-weight transposes (224 KB bf16)
    transpose_small<<<256, 256, 0, stream>>>(Wspat_w, Wref_w, Watt_w, Wg_w,
                                             WspatT, WrefT, WattT, WgT);

    // 2) Pp/Po/Pc batched, barrier-free
    gemm3<<<dim3(8, 33), 256, 0, stream>>>(people, objects, context, Wvis_w,
                                           Ppb, Pob, Pcb);

    // 3) fused aho / p_att / fref / i_ho / p_ref
    mega<<<512, 256, 0, stream>>>(spatial, WspatT, Wspat_b,
                                  Ppb, Pob, Pcb, Wvis_b,
                                  WrefT, Wref_b, WattT, Watt_b,
                                  Wip_w, Wip_b,
                                  outI, outRef, outAtt, adjw);

    // 4) graph-head projections, batched + barrier-free stage 1
    relu_proj2<<<dim3(32, 16, 2), 256, 0, stream>>>(people, objects,
        Who_w, Who_b, Woh_w, Woh_b, WgT, Yh, Zo);
    gemm_bt32b<<<dim3(8, 8, 2), 256, 0, stream>>>(people, objects, WgT, Hp, HoF);

    // 5) p_graph assembly
    pgraph2<<<64, 256, 0, stream>>>(adjw, Hp, HoF, Yh, Zo, Wg_b, outG);
}